// Round 12
// baseline (1372.379 us; speedup 1.0000x reference)
//
#include <hip/hip_runtime.h>

#define TT  64
#define BSZ 512
#define ISZ 512
#define HSZ 1024

typedef short bf16x8 __attribute__((ext_vector_type(8)));
typedef float f32x4 __attribute__((ext_vector_type(4)));
typedef unsigned short u16x8 __attribute__((ext_vector_type(8)));

typedef const __attribute__((address_space(1))) unsigned int* gas_t;
typedef __attribute__((address_space(3))) unsigned int* las_t;

__device__ __forceinline__ unsigned short f2bf(float f) {
    unsigned int u = __float_as_uint(f);
    unsigned int r = u + 0x7FFFu + ((u >> 16) & 1u);   // RNE
    return (unsigned short)(r >> 16);
}
__device__ __forceinline__ float bf2f(unsigned short u) {
    return __uint_as_float(((unsigned int)u) << 16);
}

__global__ void cast_f32_to_bf16(const float* __restrict__ in,
                                 unsigned short* __restrict__ out, int n8) {
    int i = blockIdx.x * blockDim.x + threadIdx.x;
    if (i >= n8) return;
    const float4* p = (const float4*)(in + (size_t)i * 8);
    float4 v0 = p[0], v1 = p[1];
    u16x8 o;
    o[0] = f2bf(v0.x); o[1] = f2bf(v0.y); o[2] = f2bf(v0.z); o[3] = f2bf(v0.w);
    o[4] = f2bf(v1.x); o[5] = f2bf(v1.y); o[6] = f2bf(v1.z); o[7] = f2bf(v1.w);
    *(u16x8*)(out + (size_t)i * 8) = o;
}

__global__ void bias_combine(const float* __restrict__ a,
                             const float* __restrict__ b,
                             float* __restrict__ o) {
    int i = blockIdx.x * blockDim.x + threadIdx.x;
    if (i < 4 * HSZ) o[i] = a[i] + b[i];
}

__global__ void zero_arr(int* p, int n) {
    int i = blockIdx.x * blockDim.x + threadIdx.x;
    if (i < n) p[i] = 0;
}

// ---------------- Phase 1: XG[t] = x_t @ Wih^T + bias, bf16 -----------------
// Output in CONSUMER layout: [t][mi(4)][ni(64)][tid(512)][16(g*4+r)] so that
// phase 2 loads its per-thread xg as two contiguous b128.
__global__ __launch_bounds__(256) void xg_gemm(
    const unsigned short* __restrict__ xb,    // [TT,512,512] bf16
    const unsigned short* __restrict__ Wihb,  // [4096,512] bf16
    const float* __restrict__ bias,           // [4096]
    unsigned short* __restrict__ XG)          // [TT][4][64][512][16] bf16
{
    __shared__ unsigned short Ab[2][128 * 64];
    __shared__ unsigned short Wb[2][128 * 64];

    const int t   = blockIdx.x >> 7;
    const int j   = blockIdx.x & 127;
    const int xcd = j & 7;
    const int idx = j >> 3;
    const int hh0 = (xcd * 4 + (idx & 3)) * 32;
    const int bb0 = (idx >> 2) * 128;

    const unsigned short* A = xb + (size_t)t * BSZ * ISZ;

    const int lane = threadIdx.x & 63;
    const int wv   = threadIdx.x >> 6;
    const int wx   = wv & 1;
    const int wy   = wv >> 1;
    const int lr   = lane & 15;
    const int kq   = lane >> 4;

    const f32x4 z = {0.f, 0.f, 0.f, 0.f};
    f32x4 acc[4][4];
    #pragma unroll
    for (int m = 0; m < 4; ++m)
        #pragma unroll
        for (int g = 0; g < 4; ++g) acc[m][g] = z;

    auto stage = [&](int k0, unsigned short* Abuf, unsigned short* Wbuf) {
        const int sub = lane >> 3;
        const int swk = ((lane & 7) ^ sub) * 8;
        #pragma unroll
        for (int i = 0; i < 4; ++i) {
            const int tr8 = (wv * 4 + i) * 8;
            const unsigned short* g = A + (size_t)(bb0 + tr8 + sub) * ISZ + k0 + swk;
            __builtin_amdgcn_global_load_lds((gas_t)g, (las_t)(Abuf + tr8 * 64), 16, 0, 0);
        }
        #pragma unroll
        for (int i = 0; i < 4; ++i) {
            const int tr8 = (wv * 4 + i) * 8;
            const int tr = tr8 + sub;
            const int wrow = hh0 + (tr & 31) + (tr >> 5) * 1024;
            const unsigned short* g = Wihb + (size_t)wrow * ISZ + k0 + swk;
            __builtin_amdgcn_global_load_lds((gas_t)g, (las_t)(Wbuf + tr8 * 64), 16, 0, 0);
        }
    };

    stage(0, Ab[0], Wb[0]);
    const int swz = (lr & 7) << 4;
    for (int c = 0; c < 8; ++c) {
        const int buf = c & 1;
        if (c + 1 < 8) {
            stage((c + 1) * 64, Ab[buf ^ 1], Wb[buf ^ 1]);
            asm volatile("s_waitcnt vmcnt(8)" ::: "memory");
        } else {
            asm volatile("s_waitcnt vmcnt(0)" ::: "memory");
        }
        __builtin_amdgcn_sched_barrier(0);
        __builtin_amdgcn_s_barrier();

        const char* Ac = (const char*)Ab[buf];
        const char* Wc = (const char*)Wb[buf];
        #pragma unroll
        for (int ks = 0; ks < 2; ++ks) {
            const int kb = ks * 64 + kq * 16;
            bf16x8 wf[4], af[4];
            #pragma unroll
            for (int g = 0; g < 4; ++g) {
                const int tr = g * 32 + wx * 16 + lr;
                wf[g] = *(const bf16x8*)(Wc + tr * 128 + (kb ^ swz));
            }
            #pragma unroll
            for (int m = 0; m < 4; ++m) {
                const int tr = wy * 64 + m * 16 + lr;
                af[m] = *(const bf16x8*)(Ac + tr * 128 + (kb ^ swz));
            }
            #pragma unroll
            for (int m = 0; m < 4; ++m)
                #pragma unroll
                for (int g = 0; g < 4; ++g)
                    acc[m][g] = __builtin_amdgcn_mfma_f32_16x16x32_bf16(af[m], wf[g], acc[m][g], 0, 0, 0);
        }
        __builtin_amdgcn_s_barrier();
    }

    // ---- epilogue: scatter into consumer layout ----
    const int n = hh0 + wx * 16 + lr;
    float bv[4];
    #pragma unroll
    for (int g = 0; g < 4; ++g) bv[g] = bias[g * HSZ + n];
    unsigned short* XGt = XG + (size_t)t * (4 * 64 * 8192);
    const size_t slab = ((size_t)(bb0 >> 7) * 64 + (n >> 4)) * 8192;
    #pragma unroll
    for (int m = 0; m < 4; ++m) {
        const int tid_c = ((m & 1) * 4 + wy * 2 + (m >> 1)) * 64 + kq * 16 + lr;
        u16x8 o0, o1;
        #pragma unroll
        for (int g = 0; g < 4; ++g)
            #pragma unroll
            for (int r = 0; r < 4; ++r) {
                const unsigned short v = f2bf(acc[m][g][r] + bv[g]);
                if (g < 2) o0[g * 4 + r] = v;
                else       o1[(g - 2) * 4 + r] = v;
            }
        *(u16x8*)(XGt + slab + (size_t)tid_c * 16) = o0;
        *(u16x8*)(XGt + slab + (size_t)tid_c * 16 + 8) = o1;
    }
}

// ---------------- Phase 2: recurrence only ---------------------------------
// 256 blocks (1/CU via 144KB LDS), 512 thr = 8 waves (2/SIMD).
// XCD-CLOSED mi groups: mi = (bid&7)>>1 -> each mi-group (an independent
// sub-LSTM over 128 batch rows) lives on one XCD pair; h traffic never
// leaves the pair's L2s. ni = (bid>>3) + ((bid&1)<<5).
// mg = wv&3 (32 b-rows), ks = wv>>2 (K half). W_hh slice LDS-resident.
// h rotates through 64 per-step buffers [ni'][512][16] (no acquire fences).
__global__ __launch_bounds__(512, 2) void lstm_rec(
    const unsigned short* __restrict__ XG,    // [TT][4][64][512][16] bf16
    const unsigned short* __restrict__ Whhb,  // [4096,1024] bf16
    float* __restrict__ out,
    unsigned short* __restrict__ hbs,         // [TT][64][512][16]
    int* __restrict__ arrive)
{
    __shared__ unsigned short WhL[64 * 1024];   // 128 KiB persistent W_hh
    __shared__ float WS[4096];                  //  16 KiB exchange

    const int tid  = threadIdx.x;
    const int lane = tid & 63;
    const int wv   = tid >> 6;
    const int mg   = wv & 3;
    const int ks   = wv >> 2;
    const int lr   = lane & 15;
    const int kq   = lane >> 4;
    const int bid  = blockIdx.x;
    const int mi   = (bid & 7) >> 1;
    const int ni   = (bid >> 3) + ((bid & 1) << 5);
    const int b0   = mi * 128;
    const int hc0  = ni * 16;

    // ---- stage persistent W_hh slice. LDS[r][slot u] = G[r][u^(r&7)] ----
    #pragma unroll
    for (int i = 0; i < 16; ++i) {
        const int li = wv * 16 + i;
        const int r = li >> 1, half = li & 1;
        const int grow = (r >> 4) * HSZ + hc0 + (r & 15);
        const int gslot = (half * 64 + lane) ^ (r & 7);
        const unsigned short* g = Whhb + (size_t)grow * HSZ + (size_t)gslot * 8;
        __builtin_amdgcn_global_load_lds((gas_t)g, (las_t)(WhL + li * 512), 16, 0, 0);
    }

    const int bth = b0 + mg * 32 + ks * 16 + kq * 4;   // this thread's 4 rows
    const int n   = hc0 + lr;
    const unsigned short* xgtb = XG + ((size_t)mi * 64 + ni) * 8192 + (size_t)tid * 16;

    bf16x8 xg0 = *(const bf16x8*)(xgtb);       // t = 0
    bf16x8 xg1 = *(const bf16x8*)(xgtb + 8);

    auto h_gemm = [&](const unsigned short* hp, f32x4 (&acc)[2][4]) {
        const int br0 = b0 + mg * 32 + lr;
        bf16x8 a[2][16];
        #pragma unroll
        for (int c = 0; c < 16; ++c) {                    // all 32 loads upfront
            const int kc = ks * 512 + c * 32 + kq * 8;
            const size_t base = (size_t)(kc >> 4) * 8192 + (kc & 15);
            a[0][c] = *(const bf16x8*)(hp + base + (size_t)br0 * 16);
            a[1][c] = *(const bf16x8*)(hp + base + (size_t)(br0 + 16) * 16);
        }
        #pragma unroll
        for (int c = 0; c < 16; ++c) {
            const int u0 = ks * 64 + c * 4 + kq;
            const int woff = ((u0 ^ (lr & 7)) << 4);
            #pragma unroll
            for (int g = 0; g < 4; ++g) {
                bf16x8 wf = *(const bf16x8*)((const char*)WhL + (g * 16 + lr) * 2048 + woff);
                acc[0][g] = __builtin_amdgcn_mfma_f32_16x16x32_bf16(a[0][c], wf, acc[0][g], 0, 0, 0);
                acc[1][g] = __builtin_amdgcn_mfma_f32_16x16x32_bf16(a[1][c], wf, acc[1][g], 0, 0, 0);
            }
        }
    };

    asm volatile("s_waitcnt vmcnt(0)" ::: "memory");   // W_hh + xg(0) ready
    __syncthreads();

    float* hn = out + (size_t)TT * BSZ * HSZ;
    float* cn = hn + (size_t)BSZ * HSZ;
    f32x4 creg = {0.f, 0.f, 0.f, 0.f};

    for (int t = 0; t < TT; ++t) {
        f32x4 accf[4];
        if (t > 0) {
            const f32x4 z = {0.f, 0.f, 0.f, 0.f};
            f32x4 acc[2][4];
            #pragma unroll
            for (int m = 0; m < 2; ++m)
                #pragma unroll
                for (int g = 0; g < 4; ++g) acc[m][g] = z;
            h_gemm(hbs + (size_t)(t - 1) * 524288, acc);

            // ---- 3-barrier ks exchange ----
            if (ks == 1) {
                #pragma unroll
                for (int g = 0; g < 4; ++g)
                    *(f32x4*)&WS[mg * 1024 + g * 256 + lane * 4] = acc[0][g];
            }
            __syncthreads();
            if (ks == 0) {
                #pragma unroll
                for (int g = 0; g < 4; ++g)
                    accf[g] = acc[0][g] + *(const f32x4*)&WS[mg * 1024 + g * 256 + lane * 4];
            }
            __syncthreads();
            if (ks == 0) {
                #pragma unroll
                for (int g = 0; g < 4; ++g)
                    *(f32x4*)&WS[mg * 1024 + g * 256 + lane * 4] = acc[1][g];
            }
            __syncthreads();
            if (ks == 1) {
                #pragma unroll
                for (int g = 0; g < 4; ++g)
                    accf[g] = acc[1][g] + *(const f32x4*)&WS[mg * 1024 + g * 256 + lane * 4];
            }
        } else {
            #pragma unroll
            for (int g = 0; g < 4; ++g) accf[g] = (f32x4){0.f, 0.f, 0.f, 0.f};
        }

        // ---- LSTM pointwise (all 8 waves; rows bth..bth+3) ----
        unsigned short* hslab = hbs + (size_t)t * 524288 + (size_t)ni * 8192;
        float hv[4];
        #pragma unroll
        for (int r = 0; r < 4; ++r) {
            float gi = accf[0][r] + bf2f((unsigned short)xg0[r]);
            float gf = accf[1][r] + bf2f((unsigned short)xg0[4 + r]);
            float gg = accf[2][r] + bf2f((unsigned short)xg1[r]);
            float go = accf[3][r] + bf2f((unsigned short)xg1[4 + r]);
            float ig = 1.f / (1.f + __expf(-gi));
            float fg = 1.f / (1.f + __expf(-gf));
            float gv = 1.f - 2.f / (__expf(2.f * gg) + 1.f);
            float og = 1.f / (1.f + __expf(-go));
            float cnew = fg * creg[r] + ig * gv;
            float h = og * (1.f - 2.f / (__expf(2.f * cnew) + 1.f));
            creg[r] = cnew;
            hv[r] = h;
            hslab[(size_t)(bth + r) * 16 + lr] = f2bf(h);
        }
        __syncthreads();   // drain hslab stores; protect WS for next step

        float* outt = out + (size_t)t * BSZ * HSZ;
        if (t + 1 < TT) {
            int* ctr = arrive + (size_t)t * 128 + mi * 32;
            if (tid == 0)
                __hip_atomic_fetch_add(ctr, 1, __ATOMIC_RELEASE, __HIP_MEMORY_SCOPE_AGENT);
            // spin filler: deferred out stores + coalesced xg(t+1) prefetch
            #pragma unroll
            for (int r = 0; r < 4; ++r)
                outt[(size_t)(bth + r) * HSZ + n] = hv[r];
            const unsigned short* xgn = xgtb + (size_t)(t + 1) * (4 * 64 * 8192);
            xg0 = *(const bf16x8*)(xgn);
            xg1 = *(const bf16x8*)(xgn + 8);
            if (tid == 0) {
                while (__hip_atomic_load(ctr, __ATOMIC_RELAXED, __HIP_MEMORY_SCOPE_AGENT) < 64)
                    __builtin_amdgcn_s_sleep(1);
            }
            __syncthreads();
        } else {
            #pragma unroll
            for (int r = 0; r < 4; ++r) {
                const size_t idx = (size_t)(bth + r) * HSZ + n;
                outt[idx] = hv[r];
                hn[idx] = hv[r];
                cn[idx] = creg[r];
            }
        }
    }
}

extern "C" void kernel_launch(void* const* d_in, const int* in_sizes, int n_in,
                              void* d_out, int out_size, void* d_ws, size_t ws_size,
                              hipStream_t stream) {
    const float* input_ = (const float*)d_in[0];
    const float* Wih = (const float*)d_in[3];
    const float* Whh = (const float*)d_in[4];
    const float* bih = (const float*)d_in[5];
    const float* bhh = (const float*)d_in[6];

    char* ws = (char*)d_ws;
    unsigned short* Wihb = (unsigned short*)(ws);                  //   4 MB
    unsigned short* Whhb = (unsigned short*)(ws + (4u << 20));     //   8 MB
    unsigned short* xb   = (unsigned short*)(ws + (12u << 20));    //  32 MB
    float*          bias = (float*)(ws + (44u << 20));             //  16 KB
    int*            arr  = (int*)(ws + (45u << 20));               //  32 KB
    unsigned short* hbs  = (unsigned short*)(ws + (46u << 20));    //  64 MB
    unsigned short* XG   = (unsigned short*)(ws + (110u << 20));   // 256 MB

    zero_arr<<<32, 256, 0, stream>>>(arr, TT * 128);
    cast_f32_to_bf16<<<1024, 256, 0, stream>>>(Wih, Wihb, (4 * HSZ * ISZ) / 8);
    cast_f32_to_bf16<<<2048, 256, 0, stream>>>(Whh, Whhb, (4 * HSZ * HSZ) / 8);
    cast_f32_to_bf16<<<8192, 256, 0, stream>>>(input_, xb, (TT * BSZ * ISZ) / 8);
    bias_combine<<<16, 256, 0, stream>>>(bih, bhh, bias);

    float* out = (float*)d_out;
    xg_gemm<<<TT * 128, 256, 0, stream>>>(xb, Wihb, bias, XG);
    lstm_rec<<<256, 512, 0, stream>>>(XG, Whhb, out, hbs, arr);
}

// Round 13
// 1280.524 us; speedup vs baseline: 1.0717x; 1.0717x over previous
//
#include <hip/hip_runtime.h>

#define TT  64
#define BSZ 512
#define ISZ 512
#define HSZ 1024

typedef short bf16x8 __attribute__((ext_vector_type(8)));
typedef float f32x4 __attribute__((ext_vector_type(4)));
typedef unsigned short u16x8 __attribute__((ext_vector_type(8)));

typedef const __attribute__((address_space(1))) unsigned int* gas_t;
typedef __attribute__((address_space(3))) unsigned int* las_t;

__device__ __forceinline__ unsigned short f2bf(float f) {
    unsigned int u = __float_as_uint(f);
    unsigned int r = u + 0x7FFFu + ((u >> 16) & 1u);   // RNE
    return (unsigned short)(r >> 16);
}
__device__ __forceinline__ float bf2f(unsigned short u) {
    return __uint_as_float(((unsigned int)u) << 16);
}

__global__ void cast_f32_to_bf16(const float* __restrict__ in,
                                 unsigned short* __restrict__ out, int n8) {
    int i = blockIdx.x * blockDim.x + threadIdx.x;
    if (i >= n8) return;
    const float4* p = (const float4*)(in + (size_t)i * 8);
    float4 v0 = p[0], v1 = p[1];
    u16x8 o;
    o[0] = f2bf(v0.x); o[1] = f2bf(v0.y); o[2] = f2bf(v0.z); o[3] = f2bf(v0.w);
    o[4] = f2bf(v1.x); o[5] = f2bf(v1.y); o[6] = f2bf(v1.z); o[7] = f2bf(v1.w);
    *(u16x8*)(out + (size_t)i * 8) = o;
}

__global__ void bias_combine(const float* __restrict__ a,
                             const float* __restrict__ b,
                             float* __restrict__ o) {
    int i = blockIdx.x * blockDim.x + threadIdx.x;
    if (i < 4 * HSZ) o[i] = a[i] + b[i];
}

__global__ void zero_arr(int* p, int n) {
    int i = blockIdx.x * blockDim.x + threadIdx.x;
    if (i < n) p[i] = 0;
}

// ---------------- Phase 1: XG[t] = x_t @ Wih^T + bias, bf16 -----------------
// Output in CONSUMER layout: [t][mi(4)][ni(64)][tid(512)][16(g*4+r)] so that
// phase 2 loads its per-thread xg as two contiguous b128.
__global__ __launch_bounds__(256) void xg_gemm(
    const unsigned short* __restrict__ xb,    // [TT,512,512] bf16
    const unsigned short* __restrict__ Wihb,  // [4096,512] bf16
    const float* __restrict__ bias,           // [4096]
    unsigned short* __restrict__ XG)          // [TT][4][64][512][16] bf16
{
    __shared__ unsigned short Ab[2][128 * 64];
    __shared__ unsigned short Wb[2][128 * 64];

    const int t   = blockIdx.x >> 7;
    const int j   = blockIdx.x & 127;
    const int xcd = j & 7;
    const int idx = j >> 3;
    const int hh0 = (xcd * 4 + (idx & 3)) * 32;
    const int bb0 = (idx >> 2) * 128;

    const unsigned short* A = xb + (size_t)t * BSZ * ISZ;

    const int lane = threadIdx.x & 63;
    const int wv   = threadIdx.x >> 6;
    const int wx   = wv & 1;
    const int wy   = wv >> 1;
    const int lr   = lane & 15;
    const int kq   = lane >> 4;

    const f32x4 z = {0.f, 0.f, 0.f, 0.f};
    f32x4 acc[4][4];
    #pragma unroll
    for (int m = 0; m < 4; ++m)
        #pragma unroll
        for (int g = 0; g < 4; ++g) acc[m][g] = z;

    auto stage = [&](int k0, unsigned short* Abuf, unsigned short* Wbuf) {
        const int sub = lane >> 3;
        const int swk = ((lane & 7) ^ sub) * 8;
        #pragma unroll
        for (int i = 0; i < 4; ++i) {
            const int tr8 = (wv * 4 + i) * 8;
            const unsigned short* g = A + (size_t)(bb0 + tr8 + sub) * ISZ + k0 + swk;
            __builtin_amdgcn_global_load_lds((gas_t)g, (las_t)(Abuf + tr8 * 64), 16, 0, 0);
        }
        #pragma unroll
        for (int i = 0; i < 4; ++i) {
            const int tr8 = (wv * 4 + i) * 8;
            const int tr = tr8 + sub;
            const int wrow = hh0 + (tr & 31) + (tr >> 5) * 1024;
            const unsigned short* g = Wihb + (size_t)wrow * ISZ + k0 + swk;
            __builtin_amdgcn_global_load_lds((gas_t)g, (las_t)(Wbuf + tr8 * 64), 16, 0, 0);
        }
    };

    stage(0, Ab[0], Wb[0]);
    const int swz = (lr & 7) << 4;
    for (int c = 0; c < 8; ++c) {
        const int buf = c & 1;
        if (c + 1 < 8) {
            stage((c + 1) * 64, Ab[buf ^ 1], Wb[buf ^ 1]);
            asm volatile("s_waitcnt vmcnt(8)" ::: "memory");
        } else {
            asm volatile("s_waitcnt vmcnt(0)" ::: "memory");
        }
        __builtin_amdgcn_sched_barrier(0);
        __builtin_amdgcn_s_barrier();

        const char* Ac = (const char*)Ab[buf];
        const char* Wc = (const char*)Wb[buf];
        #pragma unroll
        for (int ks = 0; ks < 2; ++ks) {
            const int kb = ks * 64 + kq * 16;
            bf16x8 wf[4], af[4];
            #pragma unroll
            for (int g = 0; g < 4; ++g) {
                const int tr = g * 32 + wx * 16 + lr;
                wf[g] = *(const bf16x8*)(Wc + tr * 128 + (kb ^ swz));
            }
            #pragma unroll
            for (int m = 0; m < 4; ++m) {
                const int tr = wy * 64 + m * 16 + lr;
                af[m] = *(const bf16x8*)(Ac + tr * 128 + (kb ^ swz));
            }
            #pragma unroll
            for (int m = 0; m < 4; ++m)
                #pragma unroll
                for (int g = 0; g < 4; ++g)
                    acc[m][g] = __builtin_amdgcn_mfma_f32_16x16x32_bf16(af[m], wf[g], acc[m][g], 0, 0, 0);
        }
        __builtin_amdgcn_s_barrier();
    }

    // ---- epilogue: scatter into consumer layout ----
    const int n = hh0 + wx * 16 + lr;
    float bv[4];
    #pragma unroll
    for (int g = 0; g < 4; ++g) bv[g] = bias[g * HSZ + n];
    unsigned short* XGt = XG + (size_t)t * (4 * 64 * 8192);
    const size_t slab = ((size_t)(bb0 >> 7) * 64 + (n >> 4)) * 8192;
    #pragma unroll
    for (int m = 0; m < 4; ++m) {
        const int tid_c = ((m & 1) * 4 + wy * 2 + (m >> 1)) * 64 + kq * 16 + lr;
        u16x8 o0, o1;
        #pragma unroll
        for (int g = 0; g < 4; ++g)
            #pragma unroll
            for (int r = 0; r < 4; ++r) {
                const unsigned short v = f2bf(acc[m][g][r] + bv[g]);
                if (g < 2) o0[g * 4 + r] = v;
                else       o1[(g - 2) * 4 + r] = v;
            }
        *(u16x8*)(XGt + slab + (size_t)tid_c * 16) = o0;
        *(u16x8*)(XGt + slab + (size_t)tid_c * 16 + 8) = o1;
    }
}

// ---------------- Phase 2: recurrence only ---------------------------------
// 256 blocks (1/CU via 144KB LDS), 512 thr = 8 waves (2/SIMD).
// XCD-CLOSED mi groups (mi=(bid&7)>>1). W_hh slice LDS-resident.
// h_gemm: TWO named 16-load register batches pinned with sched_barrier(0) +
// counted vmcnt -> 16+ loads always in flight (the R11 version collapsed to
// ~7 in flight at VGPR=96, serializing ~5 L2-latency rounds per step).
__global__ __launch_bounds__(512, 2) void lstm_rec(
    const unsigned short* __restrict__ XG,    // [TT][4][64][512][16] bf16
    const unsigned short* __restrict__ Whhb,  // [4096,1024] bf16
    float* __restrict__ out,
    unsigned short* __restrict__ hbs,         // [TT][64][512][16]
    int* __restrict__ arrive)
{
    __shared__ unsigned short WhL[64 * 1024];   // 128 KiB persistent W_hh
    __shared__ float WS[4096];                  //  16 KiB exchange

    const int tid  = threadIdx.x;
    const int lane = tid & 63;
    const int wv   = tid >> 6;
    const int mg   = wv & 3;
    const int ks   = wv >> 2;
    const int lr   = lane & 15;
    const int kq   = lane >> 4;
    const int bid  = blockIdx.x;
    const int mi   = (bid & 7) >> 1;
    const int ni   = (bid >> 3) + ((bid & 1) << 5);
    const int b0   = mi * 128;
    const int hc0  = ni * 16;

    // ---- stage persistent W_hh slice. LDS[r][slot u] = G[r][u^(r&7)] ----
    #pragma unroll
    for (int i = 0; i < 16; ++i) {
        const int li = wv * 16 + i;
        const int r = li >> 1, half = li & 1;
        const int grow = (r >> 4) * HSZ + hc0 + (r & 15);
        const int gslot = (half * 64 + lane) ^ (r & 7);
        const unsigned short* g = Whhb + (size_t)grow * HSZ + (size_t)gslot * 8;
        __builtin_amdgcn_global_load_lds((gas_t)g, (las_t)(WhL + li * 512), 16, 0, 0);
    }

    const int bth = b0 + mg * 32 + ks * 16 + kq * 4;   // this thread's 4 rows
    const int n   = hc0 + lr;
    const unsigned short* xgtb = XG + ((size_t)mi * 64 + ni) * 8192 + (size_t)tid * 16;

    bf16x8 xg0 = *(const bf16x8*)(xgtb);       // t = 0
    bf16x8 xg1 = *(const bf16x8*)(xgtb + 8);

    auto h_gemm = [&](const unsigned short* hp, f32x4 (&acc)[2][4]) {
        const int br0 = b0 + mg * 32 + lr;
        bf16x8 a0[2][8], a1[2][8];

        // ---- issue batch 0 (16 loads), then batch 1 (16 loads) ----
        #pragma unroll
        for (int c = 0; c < 8; ++c) {
            const int kc = ks * 512 + c * 32 + kq * 8;
            const size_t base = (size_t)(kc >> 4) * 8192 + (kc & 15);
            a0[0][c] = *(const bf16x8*)(hp + base + (size_t)br0 * 16);
            a0[1][c] = *(const bf16x8*)(hp + base + (size_t)(br0 + 16) * 16);
        }
        __builtin_amdgcn_sched_barrier(0);
        #pragma unroll
        for (int c = 0; c < 8; ++c) {
            const int kc = ks * 512 + (c + 8) * 32 + kq * 8;
            const size_t base = (size_t)(kc >> 4) * 8192 + (kc & 15);
            a1[0][c] = *(const bf16x8*)(hp + base + (size_t)br0 * 16);
            a1[1][c] = *(const bf16x8*)(hp + base + (size_t)(br0 + 16) * 16);
        }
        __builtin_amdgcn_sched_barrier(0);

        // ---- batch 0 ready (batch 1 still in flight) ----
        asm volatile("s_waitcnt vmcnt(16)" ::: "memory");
        __builtin_amdgcn_sched_barrier(0);
        #pragma unroll
        for (int c = 0; c < 8; ++c) {
            const int u0 = ks * 64 + c * 4 + kq;
            const int woff = ((u0 ^ (lr & 7)) << 4);
            #pragma unroll
            for (int g = 0; g < 4; ++g) {
                bf16x8 wf = *(const bf16x8*)((const char*)WhL + (g * 16 + lr) * 2048 + woff);
                acc[0][g] = __builtin_amdgcn_mfma_f32_16x16x32_bf16(a0[0][c], wf, acc[0][g], 0, 0, 0);
                acc[1][g] = __builtin_amdgcn_mfma_f32_16x16x32_bf16(a0[1][c], wf, acc[1][g], 0, 0, 0);
            }
        }
        __builtin_amdgcn_sched_barrier(0);

        // ---- batch 1 ----
        asm volatile("s_waitcnt vmcnt(0)" ::: "memory");
        __builtin_amdgcn_sched_barrier(0);
        #pragma unroll
        for (int c = 0; c < 8; ++c) {
            const int u0 = ks * 64 + (c + 8) * 4 + kq;
            const int woff = ((u0 ^ (lr & 7)) << 4);
            #pragma unroll
            for (int g = 0; g < 4; ++g) {
                bf16x8 wf = *(const bf16x8*)((const char*)WhL + (g * 16 + lr) * 2048 + woff);
                acc[0][g] = __builtin_amdgcn_mfma_f32_16x16x32_bf16(a1[0][c], wf, acc[0][g], 0, 0, 0);
                acc[1][g] = __builtin_amdgcn_mfma_f32_16x16x32_bf16(a1[1][c], wf, acc[1][g], 0, 0, 0);
            }
        }
    };

    asm volatile("s_waitcnt vmcnt(0)" ::: "memory");   // W_hh + xg(0) ready
    __syncthreads();

    float* hn = out + (size_t)TT * BSZ * HSZ;
    float* cn = hn + (size_t)BSZ * HSZ;
    f32x4 creg = {0.f, 0.f, 0.f, 0.f};

    for (int t = 0; t < TT; ++t) {
        f32x4 accf[4];
        if (t > 0) {
            const f32x4 z = {0.f, 0.f, 0.f, 0.f};
            f32x4 acc[2][4];
            #pragma unroll
            for (int m = 0; m < 2; ++m)
                #pragma unroll
                for (int g = 0; g < 4; ++g) acc[m][g] = z;
            h_gemm(hbs + (size_t)(t - 1) * 524288, acc);

            // ---- 3-barrier ks exchange ----
            if (ks == 1) {
                #pragma unroll
                for (int g = 0; g < 4; ++g)
                    *(f32x4*)&WS[mg * 1024 + g * 256 + lane * 4] = acc[0][g];
            }
            __syncthreads();
            if (ks == 0) {
                #pragma unroll
                for (int g = 0; g < 4; ++g)
                    accf[g] = acc[0][g] + *(const f32x4*)&WS[mg * 1024 + g * 256 + lane * 4];
            }
            __syncthreads();
            if (ks == 0) {
                #pragma unroll
                for (int g = 0; g < 4; ++g)
                    *(f32x4*)&WS[mg * 1024 + g * 256 + lane * 4] = acc[1][g];
            }
            __syncthreads();
            if (ks == 1) {
                #pragma unroll
                for (int g = 0; g < 4; ++g)
                    accf[g] = acc[1][g] + *(const f32x4*)&WS[mg * 1024 + g * 256 + lane * 4];
            }
        } else {
            #pragma unroll
            for (int g = 0; g < 4; ++g) accf[g] = (f32x4){0.f, 0.f, 0.f, 0.f};
        }

        // ---- LSTM pointwise (all 8 waves; rows bth..bth+3) ----
        unsigned short* hslab = hbs + (size_t)t * 524288 + (size_t)ni * 8192;
        float hv[4];
        #pragma unroll
        for (int r = 0; r < 4; ++r) {
            float gi = accf[0][r] + bf2f((unsigned short)xg0[r]);
            float gf = accf[1][r] + bf2f((unsigned short)xg0[4 + r]);
            float gg = accf[2][r] + bf2f((unsigned short)xg1[r]);
            float go = accf[3][r] + bf2f((unsigned short)xg1[4 + r]);
            float ig = 1.f / (1.f + __expf(-gi));
            float fg = 1.f / (1.f + __expf(-gf));
            float gv = 1.f - 2.f / (__expf(2.f * gg) + 1.f);
            float og = 1.f / (1.f + __expf(-go));
            float cnew = fg * creg[r] + ig * gv;
            float h = og * (1.f - 2.f / (__expf(2.f * cnew) + 1.f));
            creg[r] = cnew;
            hv[r] = h;
            hslab[(size_t)(bth + r) * 16 + lr] = f2bf(h);
        }
        __syncthreads();   // drain hslab stores; protect WS for next step

        float* outt = out + (size_t)t * BSZ * HSZ;
        if (t + 1 < TT) {
            int* ctr = arrive + (size_t)t * 128 + mi * 32;
            if (tid == 0)
                __hip_atomic_fetch_add(ctr, 1, __ATOMIC_RELEASE, __HIP_MEMORY_SCOPE_AGENT);
            // spin filler: deferred out stores + coalesced xg(t+1) prefetch
            #pragma unroll
            for (int r = 0; r < 4; ++r)
                outt[(size_t)(bth + r) * HSZ + n] = hv[r];
            const unsigned short* xgn = xgtb + (size_t)(t + 1) * (4 * 64 * 8192);
            xg0 = *(const bf16x8*)(xgn);
            xg1 = *(const bf16x8*)(xgn + 8);
            if (tid == 0) {
                while (__hip_atomic_load(ctr, __ATOMIC_RELAXED, __HIP_MEMORY_SCOPE_AGENT) < 64)
                    __builtin_amdgcn_s_sleep(1);
            }
            __syncthreads();
        } else {
            #pragma unroll
            for (int r = 0; r < 4; ++r) {
                const size_t idx = (size_t)(bth + r) * HSZ + n;
                outt[idx] = hv[r];
                hn[idx] = hv[r];
                cn[idx] = creg[r];
            }
        }
    }
}

extern "C" void kernel_launch(void* const* d_in, const int* in_sizes, int n_in,
                              void* d_out, int out_size, void* d_ws, size_t ws_size,
                              hipStream_t stream) {
    const float* input_ = (const float*)d_in[0];
    const float* Wih = (const float*)d_in[3];
    const float* Whh = (const float*)d_in[4];
    const float* bih = (const float*)d_in[5];
    const float* bhh = (const float*)d_in[6];

    char* ws = (char*)d_ws;
    unsigned short* Wihb = (unsigned short*)(ws);                  //   4 MB
    unsigned short* Whhb = (unsigned short*)(ws + (4u << 20));     //   8 MB
    unsigned short* xb   = (unsigned short*)(ws + (12u << 20));    //  32 MB
    float*          bias = (float*)(ws + (44u << 20));             //  16 KB
    int*            arr  = (int*)(ws + (45u << 20));               //  32 KB
    unsigned short* hbs  = (unsigned short*)(ws + (46u << 20));    //  64 MB
    unsigned short* XG   = (unsigned short*)(ws + (110u << 20));   // 256 MB

    zero_arr<<<32, 256, 0, stream>>>(arr, TT * 128);
    cast_f32_to_bf16<<<1024, 256, 0, stream>>>(Wih, Wihb, (4 * HSZ * ISZ) / 8);
    cast_f32_to_bf16<<<2048, 256, 0, stream>>>(Whh, Whhb, (4 * HSZ * HSZ) / 8);
    cast_f32_to_bf16<<<8192, 256, 0, stream>>>(input_, xb, (TT * BSZ * ISZ) / 8);
    bias_combine<<<16, 256, 0, stream>>>(bih, bhh, bias);

    float* out = (float*)d_out;
    xg_gemm<<<TT * 128, 256, 0, stream>>>(xb, Wihb, bias, XG);
    lstm_rec<<<256, 512, 0, stream>>>(XG, Whhb, out, hbs, arr);
}

// Round 14
// 1240.841 us; speedup vs baseline: 1.1060x; 1.0320x over previous
//
#include <hip/hip_runtime.h>

#define TT  64
#define BSZ 512
#define ISZ 512
#define HSZ 1024

typedef short bf16x8 __attribute__((ext_vector_type(8)));
typedef float f32x4 __attribute__((ext_vector_type(4)));
typedef unsigned short u16x8 __attribute__((ext_vector_type(8)));

typedef const __attribute__((address_space(1))) unsigned int* gas_t;
typedef __attribute__((address_space(3))) unsigned int* las_t;

__device__ __forceinline__ unsigned short f2bf(float f) {
    unsigned int u = __float_as_uint(f);
    unsigned int r = u + 0x7FFFu + ((u >> 16) & 1u);   // RNE
    return (unsigned short)(r >> 16);
}
__device__ __forceinline__ float bf2f(unsigned short u) {
    return __uint_as_float(((unsigned int)u) << 16);
}

__global__ void cast_f32_to_bf16(const float* __restrict__ in,
                                 unsigned short* __restrict__ out, int n8) {
    int i = blockIdx.x * blockDim.x + threadIdx.x;
    if (i >= n8) return;
    const float4* p = (const float4*)(in + (size_t)i * 8);
    float4 v0 = p[0], v1 = p[1];
    u16x8 o;
    o[0] = f2bf(v0.x); o[1] = f2bf(v0.y); o[2] = f2bf(v0.z); o[3] = f2bf(v0.w);
    o[4] = f2bf(v1.x); o[5] = f2bf(v1.y); o[6] = f2bf(v1.z); o[7] = f2bf(v1.w);
    *(u16x8*)(out + (size_t)i * 8) = o;
}

__global__ void bias_combine(const float* __restrict__ a,
                             const float* __restrict__ b,
                             float* __restrict__ o) {
    int i = blockIdx.x * blockDim.x + threadIdx.x;
    if (i < 4 * HSZ) o[i] = a[i] + b[i];
}

__global__ void zero_arr(int* p, int n) {
    int i = blockIdx.x * blockDim.x + threadIdx.x;
    if (i < n) p[i] = 0;
}

// ---------------- Phase 1: XG[t] = x_t @ Wih^T + bias, bf16 -----------------
// Output in CONSUMER layout: [t][mi(4)][ni(64)][tid(512)][16(g*4+r)] so that
// phase 2 loads its per-thread xg as two contiguous b128.
__global__ __launch_bounds__(256) void xg_gemm(
    const unsigned short* __restrict__ xb,    // [TT,512,512] bf16
    const unsigned short* __restrict__ Wihb,  // [4096,512] bf16
    const float* __restrict__ bias,           // [4096]
    unsigned short* __restrict__ XG)          // [TT][4][64][512][16] bf16
{
    __shared__ unsigned short Ab[2][128 * 64];
    __shared__ unsigned short Wb[2][128 * 64];

    const int t   = blockIdx.x >> 7;
    const int j   = blockIdx.x & 127;
    const int xcd = j & 7;
    const int idx = j >> 3;
    const int hh0 = (xcd * 4 + (idx & 3)) * 32;
    const int bb0 = (idx >> 2) * 128;

    const unsigned short* A = xb + (size_t)t * BSZ * ISZ;

    const int lane = threadIdx.x & 63;
    const int wv   = threadIdx.x >> 6;
    const int wx   = wv & 1;
    const int wy   = wv >> 1;
    const int lr   = lane & 15;
    const int kq   = lane >> 4;

    const f32x4 z = {0.f, 0.f, 0.f, 0.f};
    f32x4 acc[4][4];
    #pragma unroll
    for (int m = 0; m < 4; ++m)
        #pragma unroll
        for (int g = 0; g < 4; ++g) acc[m][g] = z;

    auto stage = [&](int k0, unsigned short* Abuf, unsigned short* Wbuf) {
        const int sub = lane >> 3;
        const int swk = ((lane & 7) ^ sub) * 8;
        #pragma unroll
        for (int i = 0; i < 4; ++i) {
            const int tr8 = (wv * 4 + i) * 8;
            const unsigned short* g = A + (size_t)(bb0 + tr8 + sub) * ISZ + k0 + swk;
            __builtin_amdgcn_global_load_lds((gas_t)g, (las_t)(Abuf + tr8 * 64), 16, 0, 0);
        }
        #pragma unroll
        for (int i = 0; i < 4; ++i) {
            const int tr8 = (wv * 4 + i) * 8;
            const int tr = tr8 + sub;
            const int wrow = hh0 + (tr & 31) + (tr >> 5) * 1024;
            const unsigned short* g = Wihb + (size_t)wrow * ISZ + k0 + swk;
            __builtin_amdgcn_global_load_lds((gas_t)g, (las_t)(Wbuf + tr8 * 64), 16, 0, 0);
        }
    };

    stage(0, Ab[0], Wb[0]);
    const int swz = (lr & 7) << 4;
    for (int c = 0; c < 8; ++c) {
        const int buf = c & 1;
        if (c + 1 < 8) {
            stage((c + 1) * 64, Ab[buf ^ 1], Wb[buf ^ 1]);
            asm volatile("s_waitcnt vmcnt(8)" ::: "memory");
        } else {
            asm volatile("s_waitcnt vmcnt(0)" ::: "memory");
        }
        __builtin_amdgcn_sched_barrier(0);
        __builtin_amdgcn_s_barrier();

        const char* Ac = (const char*)Ab[buf];
        const char* Wc = (const char*)Wb[buf];
        #pragma unroll
        for (int ks = 0; ks < 2; ++ks) {
            const int kb = ks * 64 + kq * 16;
            bf16x8 wf[4], af[4];
            #pragma unroll
            for (int g = 0; g < 4; ++g) {
                const int tr = g * 32 + wx * 16 + lr;
                wf[g] = *(const bf16x8*)(Wc + tr * 128 + (kb ^ swz));
            }
            #pragma unroll
            for (int m = 0; m < 4; ++m) {
                const int tr = wy * 64 + m * 16 + lr;
                af[m] = *(const bf16x8*)(Ac + tr * 128 + (kb ^ swz));
            }
            #pragma unroll
            for (int m = 0; m < 4; ++m)
                #pragma unroll
                for (int g = 0; g < 4; ++g)
                    acc[m][g] = __builtin_amdgcn_mfma_f32_16x16x32_bf16(af[m], wf[g], acc[m][g], 0, 0, 0);
        }
        __builtin_amdgcn_s_barrier();
    }

    // ---- epilogue: scatter into consumer layout ----
    const int n = hh0 + wx * 16 + lr;
    float bv[4];
    #pragma unroll
    for (int g = 0; g < 4; ++g) bv[g] = bias[g * HSZ + n];
    unsigned short* XGt = XG + (size_t)t * (4 * 64 * 8192);
    const size_t slab = ((size_t)(bb0 >> 7) * 64 + (n >> 4)) * 8192;
    #pragma unroll
    for (int m = 0; m < 4; ++m) {
        const int tid_c = ((m & 1) * 4 + wy * 2 + (m >> 1)) * 64 + kq * 16 + lr;
        u16x8 o0, o1;
        #pragma unroll
        for (int g = 0; g < 4; ++g)
            #pragma unroll
            for (int r = 0; r < 4; ++r) {
                const unsigned short v = f2bf(acc[m][g][r] + bv[g]);
                if (g < 2) o0[g * 4 + r] = v;
                else       o1[(g - 2) * 4 + r] = v;
            }
        *(u16x8*)(XGt + slab + (size_t)tid_c * 16) = o0;
        *(u16x8*)(XGt + slab + (size_t)tid_c * 16 + 8) = o1;
    }
}

// ---------------- Phase 2: recurrence only ---------------------------------
// 256 blocks (1/CU via 144KB LDS), 512 thr = 8 waves (2/SIMD).
// XCD-CLOSED mi groups (mi=(bid&7)>>1). W_hh slice LDS-resident.
// h_gemm: two pinned 16-load register batches (R12).
// Step handshake (NEW): per-producer flag array + lane-parallel poll.
//  - producer (mi,ni): ONE release store to its own 4B slot (no RMW, no
//    same-line serialization across 64 producers)
//  - consumer: wave 0, lane l spins on flags[t][mi][l]; exec-mask divergence
//    gives __all semantics; one load covers all 64 producers per round.
__global__ __launch_bounds__(512, 2) void lstm_rec(
    const unsigned short* __restrict__ XG,    // [TT][4][64][512][16] bf16
    const unsigned short* __restrict__ Whhb,  // [4096,1024] bf16
    float* __restrict__ out,
    unsigned short* __restrict__ hbs,         // [TT][64][512][16]
    int* __restrict__ flags)                  // [TT][4][64]
{
    __shared__ unsigned short WhL[64 * 1024];   // 128 KiB persistent W_hh
    __shared__ float WS[4096];                  //  16 KiB exchange

    const int tid  = threadIdx.x;
    const int lane = tid & 63;
    const int wv   = tid >> 6;
    const int mg   = wv & 3;
    const int ks   = wv >> 2;
    const int lr   = lane & 15;
    const int kq   = lane >> 4;
    const int bid  = blockIdx.x;
    const int mi   = (bid & 7) >> 1;
    const int ni   = (bid >> 3) + ((bid & 1) << 5);
    const int b0   = mi * 128;
    const int hc0  = ni * 16;

    // ---- stage persistent W_hh slice. LDS[r][slot u] = G[r][u^(r&7)] ----
    #pragma unroll
    for (int i = 0; i < 16; ++i) {
        const int li = wv * 16 + i;
        const int r = li >> 1, half = li & 1;
        const int grow = (r >> 4) * HSZ + hc0 + (r & 15);
        const int gslot = (half * 64 + lane) ^ (r & 7);
        const unsigned short* g = Whhb + (size_t)grow * HSZ + (size_t)gslot * 8;
        __builtin_amdgcn_global_load_lds((gas_t)g, (las_t)(WhL + li * 512), 16, 0, 0);
    }

    const int bth = b0 + mg * 32 + ks * 16 + kq * 4;   // this thread's 4 rows
    const int n   = hc0 + lr;
    const unsigned short* xgtb = XG + ((size_t)mi * 64 + ni) * 8192 + (size_t)tid * 16;

    bf16x8 xg0 = *(const bf16x8*)(xgtb);       // t = 0
    bf16x8 xg1 = *(const bf16x8*)(xgtb + 8);

    auto h_gemm = [&](const unsigned short* hp, f32x4 (&acc)[2][4]) {
        const int br0 = b0 + mg * 32 + lr;
        bf16x8 a0[2][8], a1[2][8];

        #pragma unroll
        for (int c = 0; c < 8; ++c) {
            const int kc = ks * 512 + c * 32 + kq * 8;
            const size_t base = (size_t)(kc >> 4) * 8192 + (kc & 15);
            a0[0][c] = *(const bf16x8*)(hp + base + (size_t)br0 * 16);
            a0[1][c] = *(const bf16x8*)(hp + base + (size_t)(br0 + 16) * 16);
        }
        __builtin_amdgcn_sched_barrier(0);
        #pragma unroll
        for (int c = 0; c < 8; ++c) {
            const int kc = ks * 512 + (c + 8) * 32 + kq * 8;
            const size_t base = (size_t)(kc >> 4) * 8192 + (kc & 15);
            a1[0][c] = *(const bf16x8*)(hp + base + (size_t)br0 * 16);
            a1[1][c] = *(const bf16x8*)(hp + base + (size_t)(br0 + 16) * 16);
        }
        __builtin_amdgcn_sched_barrier(0);

        asm volatile("s_waitcnt vmcnt(16)" ::: "memory");
        __builtin_amdgcn_sched_barrier(0);
        #pragma unroll
        for (int c = 0; c < 8; ++c) {
            const int u0 = ks * 64 + c * 4 + kq;
            const int woff = ((u0 ^ (lr & 7)) << 4);
            #pragma unroll
            for (int g = 0; g < 4; ++g) {
                bf16x8 wf = *(const bf16x8*)((const char*)WhL + (g * 16 + lr) * 2048 + woff);
                acc[0][g] = __builtin_amdgcn_mfma_f32_16x16x32_bf16(a0[0][c], wf, acc[0][g], 0, 0, 0);
                acc[1][g] = __builtin_amdgcn_mfma_f32_16x16x32_bf16(a0[1][c], wf, acc[1][g], 0, 0, 0);
            }
        }
        __builtin_amdgcn_sched_barrier(0);

        asm volatile("s_waitcnt vmcnt(0)" ::: "memory");
        __builtin_amdgcn_sched_barrier(0);
        #pragma unroll
        for (int c = 0; c < 8; ++c) {
            const int u0 = ks * 64 + (c + 8) * 4 + kq;
            const int woff = ((u0 ^ (lr & 7)) << 4);
            #pragma unroll
            for (int g = 0; g < 4; ++g) {
                bf16x8 wf = *(const bf16x8*)((const char*)WhL + (g * 16 + lr) * 2048 + woff);
                acc[0][g] = __builtin_amdgcn_mfma_f32_16x16x32_bf16(a1[0][c], wf, acc[0][g], 0, 0, 0);
                acc[1][g] = __builtin_amdgcn_mfma_f32_16x16x32_bf16(a1[1][c], wf, acc[1][g], 0, 0, 0);
            }
        }
    };

    asm volatile("s_waitcnt vmcnt(0)" ::: "memory");   // W_hh + xg(0) ready
    __syncthreads();

    float* hn = out + (size_t)TT * BSZ * HSZ;
    float* cn = hn + (size_t)BSZ * HSZ;
    f32x4 creg = {0.f, 0.f, 0.f, 0.f};

    for (int t = 0; t < TT; ++t) {
        f32x4 accf[4];
        if (t > 0) {
            const f32x4 z = {0.f, 0.f, 0.f, 0.f};
            f32x4 acc[2][4];
            #pragma unroll
            for (int m = 0; m < 2; ++m)
                #pragma unroll
                for (int g = 0; g < 4; ++g) acc[m][g] = z;
            h_gemm(hbs + (size_t)(t - 1) * 524288, acc);

            // ---- 3-barrier ks exchange ----
            if (ks == 1) {
                #pragma unroll
                for (int g = 0; g < 4; ++g)
                    *(f32x4*)&WS[mg * 1024 + g * 256 + lane * 4] = acc[0][g];
            }
            __syncthreads();
            if (ks == 0) {
                #pragma unroll
                for (int g = 0; g < 4; ++g)
                    accf[g] = acc[0][g] + *(const f32x4*)&WS[mg * 1024 + g * 256 + lane * 4];
            }
            __syncthreads();
            if (ks == 0) {
                #pragma unroll
                for (int g = 0; g < 4; ++g)
                    *(f32x4*)&WS[mg * 1024 + g * 256 + lane * 4] = acc[1][g];
            }
            __syncthreads();
            if (ks == 1) {
                #pragma unroll
                for (int g = 0; g < 4; ++g)
                    accf[g] = acc[1][g] + *(const f32x4*)&WS[mg * 1024 + g * 256 + lane * 4];
            }
        } else {
            #pragma unroll
            for (int g = 0; g < 4; ++g) accf[g] = (f32x4){0.f, 0.f, 0.f, 0.f};
        }

        // ---- LSTM pointwise (all 8 waves; rows bth..bth+3) ----
        unsigned short* hslab = hbs + (size_t)t * 524288 + (size_t)ni * 8192;
        float hv[4];
        #pragma unroll
        for (int r = 0; r < 4; ++r) {
            float gi = accf[0][r] + bf2f((unsigned short)xg0[r]);
            float gf = accf[1][r] + bf2f((unsigned short)xg0[4 + r]);
            float gg = accf[2][r] + bf2f((unsigned short)xg1[r]);
            float go = accf[3][r] + bf2f((unsigned short)xg1[4 + r]);
            float ig = 1.f / (1.f + __expf(-gi));
            float fg = 1.f / (1.f + __expf(-gf));
            float gv = 1.f - 2.f / (__expf(2.f * gg) + 1.f);
            float og = 1.f / (1.f + __expf(-go));
            float cnew = fg * creg[r] + ig * gv;
            float h = og * (1.f - 2.f / (__expf(2.f * cnew) + 1.f));
            creg[r] = cnew;
            hv[r] = h;
            hslab[(size_t)(bth + r) * 16 + lr] = f2bf(h);
        }
        __syncthreads();   // drain hslab stores; protect WS for next step

        float* outt = out + (size_t)t * BSZ * HSZ;
        if (t + 1 < TT) {
            // ---- arrival: ONE release store to own slot (no RMW contention) ----
            if (tid == 0)
                __hip_atomic_store(flags + ((size_t)t * 4 + mi) * 64 + ni, 1,
                                   __ATOMIC_RELEASE, __HIP_MEMORY_SCOPE_AGENT);
            // spin filler: deferred out stores + coalesced xg(t+1) prefetch
            #pragma unroll
            for (int r = 0; r < 4; ++r)
                outt[(size_t)(bth + r) * HSZ + n] = hv[r];
            const unsigned short* xgn = xgtb + (size_t)(t + 1) * (4 * 64 * 8192);
            xg0 = *(const bf16x8*)(xgn);
            xg1 = *(const bf16x8*)(xgn + 8);
            // ---- lane-parallel poll: lane l waits on producer l's flag ----
            if (wv == 0) {
                const int* fp = flags + ((size_t)t * 4 + mi) * 64 + lane;
                while (__hip_atomic_load(fp, __ATOMIC_RELAXED, __HIP_MEMORY_SCOPE_AGENT) == 0)
                    __builtin_amdgcn_s_sleep(2);
            }
            __syncthreads();
        } else {
            #pragma unroll
            for (int r = 0; r < 4; ++r) {
                const size_t idx = (size_t)(bth + r) * HSZ + n;
                outt[idx] = hv[r];
                hn[idx] = hv[r];
                cn[idx] = creg[r];
            }
        }
    }
}

extern "C" void kernel_launch(void* const* d_in, const int* in_sizes, int n_in,
                              void* d_out, int out_size, void* d_ws, size_t ws_size,
                              hipStream_t stream) {
    const float* input_ = (const float*)d_in[0];
    const float* Wih = (const float*)d_in[3];
    const float* Whh = (const float*)d_in[4];
    const float* bih = (const float*)d_in[5];
    const float* bhh = (const float*)d_in[6];

    char* ws = (char*)d_ws;
    unsigned short* Wihb = (unsigned short*)(ws);                  //   4 MB
    unsigned short* Whhb = (unsigned short*)(ws + (4u << 20));     //   8 MB
    unsigned short* xb   = (unsigned short*)(ws + (12u << 20));    //  32 MB
    float*          bias = (float*)(ws + (44u << 20));             //  16 KB
    int*            flg  = (int*)(ws + (45u << 20));               //  64 KB
    unsigned short* hbs  = (unsigned short*)(ws + (46u << 20));    //  64 MB
    unsigned short* XG   = (unsigned short*)(ws + (110u << 20));   // 256 MB

    zero_arr<<<64, 256, 0, stream>>>(flg, TT * 4 * 64);
    cast_f32_to_bf16<<<1024, 256, 0, stream>>>(Wih, Wihb, (4 * HSZ * ISZ) / 8);
    cast_f32_to_bf16<<<2048, 256, 0, stream>>>(Whh, Whhb, (4 * HSZ * HSZ) / 8);
    cast_f32_to_bf16<<<8192, 256, 0, stream>>>(input_, xb, (TT * BSZ * ISZ) / 8);
    bias_combine<<<16, 256, 0, stream>>>(bih, bhh, bias);

    float* out = (float*)d_out;
    xg_gemm<<<TT * 128, 256, 0, stream>>>(xb, Wihb, bias, XG);
    lstm_rec<<<256, 512, 0, stream>>>(XG, Whhb, out, hbs, flg);
}